// Round 8
// baseline (162.190 us; speedup 1.0000x reference)
//
#include <hip/hip_runtime.h>

// tp=4, T=4096, H=8192 (from setup_inputs).
constexpr int TP  = 4;
constexpr int TT  = 4096;
constexpr int HH  = 8192;
constexpr int BLK = 256;                 // 4 waves; 32KB LDS -> 5 blocks/CU
constexpr int NJ  = HH / (BLK * 4);      // 8 float4 chunks per thread

typedef float f32x4 __attribute__((ext_vector_type(4)));

// 16B-granular XOR swizzle: spreads 512B-strided accesses across bank quads.
// Phase-2 scalar chain reads (stride 32B, leaf stride 512B) become a uniform
// 2-way conflict (free, m136).
__device__ __forceinline__ unsigned swz(unsigned byte) {
    return byte ^ (((byte >> 9) & 7u) << 4);
}

// Barrier with LDS-ordering only (s_waitcnt lgkmcnt(0) + s_barrier).
// Unlike __syncthreads (vmcnt(0) drain), in-flight nontemporal stores keep
// streaming across phases. Both uses below only need LDS visibility.
__device__ __forceinline__ void barrier_lgkm() {
    asm volatile("s_waitcnt lgkmcnt(0)" ::: "memory");
    __builtin_amdgcn_s_barrier();
    asm volatile("" ::: "memory");
}

// Exact RNE to fp8-e4m3fn grid, all-f32 (passed R6/R7 at absmax 0.125).
// Input already clipped to [-448, 448]. Normals (|n| >= 2^-6): integer
// round-half-to-even dropping 20 mantissa bits (carry into exponent correct;
// 448 closed under it). Subnormals: exact pow-2 scaling + v_rndne_f32.
__device__ __forceinline__ float fp8_rne_f(float n) {
    unsigned u = __float_as_uint(n);
    unsigned un = (u + 0x7FFFFu + ((u >> 20) & 1u)) & 0xFFF00000u;
    float qs = rintf(__fmul_rn(n, 512.0f)) * (1.0f / 512.0f);
    return ((u & 0x7FFFFFFFu) >= 0x3C800000u) ? __uint_as_float(un) : qs;
}

__global__ __launch_bounds__(BLK, 5) void fused_ar_rms_fp8(
    const float* __restrict__ input,     // [TP, T, H]
    const float* __restrict__ residual,  // [T, H]
    const float* __restrict__ weight,    // [H]
    const float* __restrict__ scale,     // [1]
    float* __restrict__ quant,           // [T, H]
    float* __restrict__ resid_out)       // [T, H]
{
    __shared__ float lds[HH];            // 32 KB, swizzled staging of s
    __shared__ float sred[4];            // per-wave partials

    const int t   = blockIdx.x;
    const int tid = threadIdx.x;
    const size_t row   = (size_t)t * HH;
    const size_t plane = (size_t)TT * HH;

    const f32x4* i0 = (const f32x4*)(input + row);
    const f32x4* i1 = (const f32x4*)(input + plane + row);
    const f32x4* i2 = (const f32x4*)(input + 2 * plane + row);
    const f32x4* i3 = (const f32x4*)(input + 3 * plane + row);
    const f32x4* rr = (const f32x4*)(residual + row);
    f32x4* qo = (f32x4*)(quant + row);
    f32x4* ro = (f32x4*)(resid_out + row);
    const f32x4* wv = (const f32x4*)weight;

    // Phase 1 — stream-burst ordering (R7 win): consume each of the 5 read
    // streams as one 8-chunk contiguous burst (8KB/wave) instead of
    // round-robin 1KB switches. Element-wise add order unchanged:
    // ((((i0+i1)+i2)+i3)+r), each step __fadd_rn — bit-identical to R6/R7.
    f32x4 A[NJ];                          // 32 registers (the running sum)

    #pragma unroll
    for (int j = 0; j < NJ; ++j)
        A[j] = __builtin_nontemporal_load(&i0[j * BLK + tid]);

    #pragma unroll
    for (int j = 0; j < NJ; ++j) {
        f32x4 b = __builtin_nontemporal_load(&i1[j * BLK + tid]);
        #pragma unroll
        for (int k = 0; k < 4; ++k) A[j][k] = __fadd_rn(A[j][k], b[k]);
    }
    #pragma unroll
    for (int j = 0; j < NJ; ++j) {
        f32x4 b = __builtin_nontemporal_load(&i2[j * BLK + tid]);
        #pragma unroll
        for (int k = 0; k < 4; ++k) A[j][k] = __fadd_rn(A[j][k], b[k]);
    }
    #pragma unroll
    for (int j = 0; j < NJ; ++j) {
        f32x4 b = __builtin_nontemporal_load(&i3[j * BLK + tid]);
        #pragma unroll
        for (int k = 0; k < 4; ++k) A[j][k] = __fadd_rn(A[j][k], b[k]);
    }
    #pragma unroll
    for (int j = 0; j < NJ; ++j) {
        const int idx = j * BLK + tid;
        f32x4 b = __builtin_nontemporal_load(&rr[idx]);
        f32x4 sv;
        #pragma unroll
        for (int k = 0; k < 4; ++k) sv[k] = __fadd_rn(A[j][k], b[k]);
        A[j] = sv;
        *(f32x4*)((char*)lds + swz(16u * (unsigned)idx)) = sv;
        __builtin_nontemporal_store(sv, &ro[idx]);
    }
    barrier_lgkm();   // LDS visibility only; ro stores keep streaming

    // Phase 2 (all 256 threads, 2 chains each): bit-exact numpy pairwise sum
    // of squares (identical to R6/R7). 64 leaves of 128, 8-acc chains of 16
    // steps, ((r0+r1)+(r2+r3))+((r4+r5)+(r6+r7)), perfect tree over leaves.
    {
        const int wave = tid >> 6;
        const int lane = tid & 63;
        const int leaf = wave * 16 + (lane >> 2);
        const unsigned baseL = (unsigned)(leaf * 512 + (lane & 3) * 4);
        const char* lp = (const char*)lds;

        float xl = *(const float*)(lp + swz(baseL));
        float xh = *(const float*)(lp + swz(baseL + 16));
        float rL = __fmul_rn(xl, xl);
        float rH = __fmul_rn(xh, xh);
        #pragma unroll
        for (int i = 1; i < 16; ++i) {
            xl = *(const float*)(lp + swz(baseL + 32u * i));
            xh = *(const float*)(lp + swz(baseL + 32u * i + 16));
            rL = __fadd_rn(rL, __fmul_rn(xl, xl));
            rH = __fadd_rn(rH, __fmul_rn(xh, xh));
        }
        rL = __fadd_rn(rL, __shfl_xor(rL, 1, 64));
        rL = __fadd_rn(rL, __shfl_xor(rL, 2, 64));
        rH = __fadd_rn(rH, __shfl_xor(rH, 1, 64));
        rH = __fadd_rn(rH, __shfl_xor(rH, 2, 64));
        float r = __fadd_rn(rL, rH);      // leaf total, exact numpy combine
        r = __fadd_rn(r, __shfl_xor(r, 4, 64));
        r = __fadd_rn(r, __shfl_xor(r, 8, 64));
        r = __fadd_rn(r, __shfl_xor(r, 16, 64));
        r = __fadd_rn(r, __shfl_xor(r, 32, 64));
        if (lane == 0) sred[wave] = r;
    }
    barrier_lgkm();   // LDS visibility only

    // Top 2 tree levels over the 4 wave partials — every thread redundantly.
    const float res = __fadd_rn(__fadd_rn(sred[0], sred[1]),
                                __fadd_rn(sred[2], sred[3]));
    const float mean = __fmul_rn(res, 1.0f / 8192.0f);   // exact pow2
    const float vv   = __fadd_rn(mean, 1e-6f);
    const float rinv = __fdiv_rn(1.0f, __fsqrt_rn(vv));  // 1/np.sqrt
    const float sc   = scale[0];

    // Phase 3: norm = ((s*rinv)*w)*sc, clip, exact fp8 RNE, store.
    #pragma unroll
    for (int j = 0; j < NJ; ++j) {
        const int idx = j * BLK + tid;
        f32x4 w4 = wv[idx];
        f32x4 qv;
        #pragma unroll
        for (int k = 0; k < 4; ++k) {
            float n = __fmul_rn(A[j][k], rinv);
            n = __fmul_rn(n, w4[k]);
            n = __fmul_rn(n, sc);
            n = fminf(fmaxf(n, -448.0f), 448.0f);
            qv[k] = fp8_rne_f(n);
        }
        __builtin_nontemporal_store(qv, &qo[idx]);
    }
}

extern "C" void kernel_launch(void* const* d_in, const int* in_sizes, int n_in,
                              void* d_out, int out_size, void* d_ws, size_t ws_size,
                              hipStream_t stream) {
    const float* input    = (const float*)d_in[0];
    const float* residual = (const float*)d_in[1];
    const float* weight   = (const float*)d_in[2];
    const float* scale    = (const float*)d_in[3];
    float* quant     = (float*)d_out;
    float* resid_out = (float*)d_out + (size_t)TT * HH;

    fused_ar_rms_fp8<<<TT, BLK, 0, stream>>>(input, residual, weight, scale,
                                             quant, resid_out);
}